// Round 10
// baseline (203.999 us; speedup 1.0000x reference)
//
#include <hip/hip_runtime.h>
#include <stdint.h>

#define N_ROWS 16384
#define M_ROWS 16384
#define KDIM   512
#define BM 128           // 4 waves x 32 rows (R10: halved per-wave rows for TLP)
#define BNT 32           // cols per bt tile
#define BKP 128          // k per phase-sub-buffer (one MFMA K)
#define NCHUNK 16
#define CHUNK_ROWS (M_ROWS / NCHUNK)       // 1024
#define BT_PER_CHUNK (CHUNK_ROWS / BNT)    // 32

typedef int intx4 __attribute__((ext_vector_type(4)));
typedef int intx8 __attribute__((ext_vector_type(8)));
typedef float floatx4 __attribute__((ext_vector_type(4)));

#define UNIT_SCALE 0x7F7F7F7F  // E8M0 exponent 127 -> 2^0 = 1.0 in every byte

__device__ __forceinline__ void async_ld16(const uint8_t* g, uint8_t* l) {
  __builtin_amdgcn_global_load_lds(
      (const __attribute__((address_space(1))) void*)g,
      (__attribute__((address_space(3))) void*)l, 16, 0, 0);
}

// Kernel 1: fp32 -> fp8 e4m3 (unit scale; |x|<=~5.5 fits e4m3 range 448)
// + per-row squared norms in exact fp32. One wave per row.
__global__ void conv_kernel(const float* __restrict__ A, const float* __restrict__ B,
                            uint8_t* __restrict__ Ah8, uint8_t* __restrict__ Bh8,
                            float* __restrict__ sq1, float* __restrict__ sq2) {
  const int lane = threadIdx.x & 63;
  const int wv = threadIdx.x >> 6;
  int row = blockIdx.x * 4 + wv;
  const float* src;
  uint8_t* dst;
  float* sq;
  if (row < N_ROWS) {
    src = A + (size_t)row * KDIM;
    dst = Ah8 + (size_t)row * KDIM;
    sq = sq1 + row;
  } else {
    int r = row - N_ROWS;
    src = B + (size_t)r * KDIM;
    dst = Bh8 + (size_t)r * KDIM;
    sq = sq2 + r;
  }
  const float4* s4 = (const float4*)src;
  float4 v0 = s4[lane * 2];
  float4 v1 = s4[lane * 2 + 1];
  uint32_t w0 = 0, w1 = 0;
  w0 = __builtin_amdgcn_cvt_pk_fp8_f32(v0.x, v0.y, w0, 0);
  w0 = __builtin_amdgcn_cvt_pk_fp8_f32(v0.z, v0.w, w0, 1);
  w1 = __builtin_amdgcn_cvt_pk_fp8_f32(v1.x, v1.y, w1, 0);
  w1 = __builtin_amdgcn_cvt_pk_fp8_f32(v1.z, v1.w, w1, 1);
  uint2 pk = {w0, w1};
  ((uint2*)dst)[lane] = pk;
  float s = v0.x * v0.x + v0.y * v0.y + v0.z * v0.z + v0.w * v0.w
          + v1.x * v1.x + v1.y * v1.y + v1.z * v1.z + v1.w * v1.w;
  #pragma unroll
  for (int off = 32; off; off >>= 1) s += __shfl_down(s, off, 64);
  if (lane == 0) *sq = s;
}

// Kernel 2: fused fp8 GEMM + running-min, tile-granular double buffer,
// 32-row waves for TLP.
//
// R9 post-mortem: removing epilogue VALU (sq2-fold) dropped VALUBusy
// 29->22.7 but the wall DIDN'T move -- the serial-sum model broke; saved
// cycles became idle. Revised model: per-wave in-order execution with only
// 2 waves/SIMD -- lgkm waits / barrier skew / issue bubbles have only ONE
// cover wave. R7's TLP test never ran (spilled at VGPR cap 64 vs need
// ~190). R10 = TLP retry with a fitting footprint: 32-row waves (areg 64
// VGPR, total ~125), BNT=32 (LDS 36KB/block), grid 2048, launch_bounds
// (256,3) -> VGPR cap 170 = spill-proof; 3-4 blocks/CU, 12-16 waves/CU.
// Keeps: tile-granular dbuf, setprio, sq2-fold, swizzle, XCD pinning
// (chunks c & c+8 share XCD c%8: 1MB fp8 B per L2).
__global__ void __launch_bounds__(256, 3)
gemm_min_kernel(const uint8_t* __restrict__ Ah8, const uint8_t* __restrict__ Bh8,
                const float* __restrict__ sq2, float* __restrict__ ws_min) {
  __shared__ __align__(16) uint8_t lsB[2][4 * BNT * BKP];   // 2 x 16 KB
  __shared__ __align__(16) float sq2_lds[CHUNK_ROWS];       // 4 KB

  const int tid = threadIdx.x;
  const int lane = tid & 63;
  const int wv = tid >> 6;       // 0..3
  const int fr = lane & 15;
  const int kg = lane >> 4;      // 0..3
  const int frs = fr & 7;

  const int bid = blockIdx.x;
  const int chunk = bid & 15;
  const int rowBase = (bid >> 4) * BM;
  const int colBase0 = chunk * CHUNK_ROWS;

  // Staging: per p-sub-buffer (32 cols x 128 k = 4 KB) 4 slots of 1KB
  // (slot = 8 cols x 128 B); wave wv stages slot wv (4 calls/wave/tile).
  // lane -> col-in-slot = lane>>3, k-chunk = lane&7, swizzle key = cis.
  const int cis = lane >> 3;                       // col in slot
  const int kofs_st = (((lane & 7) ^ cis) << 4);   // swizzled 16B source chunk

  // ---- Persistent A fragments: areg[i][p] = row (rowBase+wv*32+i*16+fr),
  // k = p*128 + kg*32 .. +32 (32 bytes = 8 VGPRs each; 8 frags = 64 VGPRs).
  intx8 areg[2][4];
  {
    const uint8_t* abase = Ah8 + (size_t)(rowBase + wv * 32 + fr) * KDIM + kg * 32;
    #pragma unroll
    for (int i = 0; i < 2; i++)
      #pragma unroll
      for (int p = 0; p < 4; p++) {
        const uint8_t* ap = abase + (size_t)i * 16 * KDIM + p * BKP;
        intx4 lo = *(const intx4*)ap;
        intx4 hi = *(const intx4*)(ap + 16);
        areg[i][p] = __builtin_shufflevector(lo, hi, 0, 1, 2, 3, 4, 5, 6, 7);
      }
  }

  // Running MAX of (inner - sq2/2); ws_min = -2 * runmax at the end.
  float runmax[2][4];
  #pragma unroll
  for (int i = 0; i < 2; i++)
    #pragma unroll
    for (int r4 = 0; r4 < 4; r4++) runmax[i][r4] = -3.0e38f;

  // Stage one 32-col x K=512 tile (16 KB): 4 calls per wave (slot = wv).
  #define STAGE_TILE(buf, cb)                                                 \
    {                                                                         \
      _Pragma("unroll")                                                       \
      for (int p_ = 0; p_ < 4; ++p_) {                                        \
        async_ld16(Bh8 + (size_t)((cb) + wv * 8 + cis) * KDIM +               \
                       p_ * BKP + kofs_st,                                    \
                   (buf) + p_ * (BNT * BKP) + (wv << 10));                    \
      }                                                                       \
    }

  // Prologue: sq2 chunk -> LDS (4 KB linear; 1 call/wave), then tile 0.
  {
    const uint8_t* s2src = (const uint8_t*)(sq2 + colBase0);
    async_ld16(s2src + (wv << 10) + lane * 16,
               ((uint8_t*)sq2_lds) + (wv << 10));
  }
  STAGE_TILE(lsB[0], colBase0)

  for (int bt = 0; bt < BT_PER_CHUNK; ++bt) {
    // All of THIS wave's stages (tile bt + sq2) landed; barrier makes every
    // wave's stages visible. stage(bt+1) is issued after the barrier (its
    // destination buffer was last read in tile bt-1, finished by all waves).
    asm volatile("s_waitcnt vmcnt(0)" ::: "memory");
    __builtin_amdgcn_s_barrier();
    __builtin_amdgcn_sched_barrier(0);

    if (bt + 1 < BT_PER_CHUNK) {
      STAGE_TILE(lsB[(bt + 1) & 1], colBase0 + (bt + 1) * BNT)
    }

    const uint8_t* cur = lsB[bt & 1];

    // sq2-folded accumulator init: acc[i][j] = -sq2[col]/2 (per-j value).
    float s2h[2];
    #pragma unroll
    for (int j = 0; j < 2; j++)
      s2h[j] = -0.5f * sq2_lds[bt * BNT + j * 16 + fr];
    floatx4 acc[2][2];
    #pragma unroll
    for (int i = 0; i < 2; i++)
      #pragma unroll
      for (int j = 0; j < 2; j++)
        acc[i][j] = (floatx4){s2h[j], s2h[j], s2h[j], s2h[j]};

    // Straight-line tile body: 16 ds_read_b128 + 16 MFMAs, no barriers.
    __builtin_amdgcn_s_setprio(1);
    #pragma unroll
    for (int p = 0; p < 4; ++p) {
      #pragma unroll
      for (int j = 0; j < 2; ++j) {
        const uint8_t* bp = cur + p * (BNT * BKP) + (j * 16 + fr) * BKP;
        intx4 lo = *(const intx4*)(bp + ((((kg << 1)) ^ frs) << 4));
        intx4 hi = *(const intx4*)(bp + ((((kg << 1) | 1) ^ frs) << 4));
        intx8 bv = __builtin_shufflevector(lo, hi, 0, 1, 2, 3, 4, 5, 6, 7);
        #pragma unroll
        for (int i = 0; i < 2; i++)
          acc[i][j] = __builtin_amdgcn_mfma_scale_f32_16x16x128_f8f6f4(
              areg[i][p], bv, acc[i][j], 0, 0,
              0, UNIT_SCALE, 0, UNIT_SCALE);
      }
    }
    __builtin_amdgcn_s_setprio(0);

    // Epilogue: pure running max (fmaf eliminated by the init fold).
    // C frag: col = j*16 + fr, row = wv*32 + i*16 + kg*4 + reg.
    #pragma unroll
    for (int j = 0; j < 2; j++)
      #pragma unroll
      for (int i = 0; i < 2; i++)
        #pragma unroll
        for (int r4 = 0; r4 < 4; r4++)
          runmax[i][r4] = fmaxf(runmax[i][r4], acc[i][j][r4]);
  }

  // Max over the 16 columns per lane row-group: butterfly on lane bits 0..3.
  #pragma unroll
  for (int i = 0; i < 2; i++)
    #pragma unroll
    for (int r4 = 0; r4 < 4; r4++) {
      float v = runmax[i][r4];
      v = fmaxf(v, __shfl_xor(v, 1, 64));
      v = fmaxf(v, __shfl_xor(v, 2, 64));
      v = fmaxf(v, __shfl_xor(v, 4, 64));
      v = fmaxf(v, __shfl_xor(v, 8, 64));
      runmax[i][r4] = v;
    }

  if (fr == 0) {
    #pragma unroll
    for (int i = 0; i < 2; i++)
      #pragma unroll
      for (int r4 = 0; r4 < 4; r4++) {
        const int lrow = wv * 32 + i * 16 + kg * 4 + r4;
        ws_min[(size_t)chunk * N_ROWS + rowBase + lrow] = -2.f * runmax[i][r4];
      }
  }
}

// Kernel 3a: per-row min across chunks + sqrt/relu, 64-block partial sums.
__global__ void partial_kernel(const float* __restrict__ ws_min,
                               const float* __restrict__ sq1,
                               float* __restrict__ part) {
  const int r = blockIdx.x * 256 + threadIdx.x;
  float m = ws_min[r];
  #pragma unroll
  for (int c = 1; c < NCHUNK; c++) m = fminf(m, ws_min[(size_t)c * N_ROWS + r]);
  float d2 = sq1[r] + m;
  d2 = d2 > 0.f ? d2 : 0.f;
  float v = sqrtf(d2) - 0.1f;
  float s = v > 0.f ? v : 0.f;
  #pragma unroll
  for (int off = 32; off; off >>= 1) s += __shfl_down(s, off, 64);
  __shared__ float ps[4];
  if ((threadIdx.x & 63) == 0) ps[threadIdx.x >> 6] = s;
  __syncthreads();
  if (threadIdx.x == 0) part[blockIdx.x] = ps[0] + ps[1] + ps[2] + ps[3];
}

// Kernel 3b: combine 64 partials.
__global__ void final_kernel(const float* __restrict__ part, float* __restrict__ out) {
  float s = part[threadIdx.x];
  #pragma unroll
  for (int off = 32; off; off >>= 1) s += __shfl_down(s, off, 64);
  if (threadIdx.x == 0) out[0] = s / (float)N_ROWS;
}

extern "C" void kernel_launch(void* const* d_in, const int* in_sizes, int n_in,
                              void* d_out, int out_size, void* d_ws, size_t ws_size,
                              hipStream_t stream) {
  const float* A = (const float*)d_in[0];
  const float* B = (const float*)d_in[1];
  char* ws = (char*)d_ws;
  const size_t fp8Bytes = (size_t)N_ROWS * KDIM;   // 8 MiB each
  uint8_t* Ah8 = (uint8_t*)ws;
  uint8_t* Bh8 = (uint8_t*)(ws + fp8Bytes);
  float* sq1 = (float*)(ws + 2 * fp8Bytes);
  float* sq2 = sq1 + N_ROWS;
  float* ws_min = sq2 + M_ROWS;
  float* part = ws_min + (size_t)NCHUNK * N_ROWS;

  conv_kernel<<<dim3((N_ROWS + M_ROWS) / 4), dim3(256), 0, stream>>>(A, B, Ah8, Bh8, sq1, sq2);
  gemm_min_kernel<<<dim3((N_ROWS / BM) * NCHUNK), dim3(256), 0, stream>>>(Ah8, Bh8, sq2, ws_min);
  partial_kernel<<<dim3(64), dim3(256), 0, stream>>>(ws_min, sq1, part);
  final_kernel<<<dim3(1), dim3(64), 0, stream>>>(part, (float*)d_out);
}

// Round 11
// 194.841 us; speedup vs baseline: 1.0470x; 1.0470x over previous
//
#include <hip/hip_runtime.h>
#include <stdint.h>

#define N_ROWS 16384
#define M_ROWS 16384
#define KDIM   512
#define BM 256           // 4 waves x 64 rows
#define BNT 64           // cols per bt tile
#define BKP 128          // k per phase-sub-buffer (one MFMA K)
#define NCHUNK 8
#define CHUNK_ROWS (M_ROWS / NCHUNK)       // 2048
#define BT_PER_CHUNK (CHUNK_ROWS / BNT)    // 32

typedef int intx4 __attribute__((ext_vector_type(4)));
typedef int intx8 __attribute__((ext_vector_type(8)));
typedef float floatx4 __attribute__((ext_vector_type(4)));

#define UNIT_SCALE 0x7F7F7F7F  // E8M0 exponent 127 -> 2^0 = 1.0 in every byte

__device__ __forceinline__ void async_ld16(const uint8_t* g, uint8_t* l) {
  __builtin_amdgcn_global_load_lds(
      (const __attribute__((address_space(1))) void*)g,
      (__attribute__((address_space(3))) void*)l, 16, 0, 0);
}

// Kernel 1: fp32 -> fp8 e4m3 (unit scale; |x|<=~5.5 fits e4m3 range 448)
// + per-row squared norms in exact fp32. One wave per row.
// R11: lane-contiguous loads (s4[lane], s4[lane+64]) -- unit-stride per
// instruction (was stride-32) -- and two coalesced dword stores.
__global__ void conv_kernel(const float* __restrict__ A, const float* __restrict__ B,
                            uint8_t* __restrict__ Ah8, uint8_t* __restrict__ Bh8,
                            float* __restrict__ sq1, float* __restrict__ sq2) {
  const int lane = threadIdx.x & 63;
  const int wv = threadIdx.x >> 6;
  int row = blockIdx.x * 4 + wv;
  const float* src;
  uint8_t* dst;
  float* sq;
  if (row < N_ROWS) {
    src = A + (size_t)row * KDIM;
    dst = Ah8 + (size_t)row * KDIM;
    sq = sq1 + row;
  } else {
    int r = row - N_ROWS;
    src = B + (size_t)r * KDIM;
    dst = Bh8 + (size_t)r * KDIM;
    sq = sq2 + r;
  }
  const float4* s4 = (const float4*)src;
  float4 v0 = s4[lane];        // elements [4*lane, 4*lane+4)
  float4 v1 = s4[lane + 64];   // elements [256+4*lane, 256+4*lane+4)
  uint32_t w0 = 0, w1 = 0;
  w0 = __builtin_amdgcn_cvt_pk_fp8_f32(v0.x, v0.y, w0, 0);
  w0 = __builtin_amdgcn_cvt_pk_fp8_f32(v0.z, v0.w, w0, 1);
  w1 = __builtin_amdgcn_cvt_pk_fp8_f32(v1.x, v1.y, w1, 0);
  w1 = __builtin_amdgcn_cvt_pk_fp8_f32(v1.z, v1.w, w1, 1);
  ((uint32_t*)dst)[lane] = w0;        // bytes [4*lane, 4*lane+4)
  ((uint32_t*)dst)[64 + lane] = w1;   // bytes [256+4*lane, ...)
  float s = v0.x * v0.x + v0.y * v0.y + v0.z * v0.z + v0.w * v0.w
          + v1.x * v1.x + v1.y * v1.y + v1.z * v1.z + v1.w * v1.w;
  #pragma unroll
  for (int off = 32; off; off >>= 1) s += __shfl_down(s, off, 64);
  if (lane == 0) *sq = s;
}

// Kernel 2: fused fp8 GEMM + running-min, TILE-granular double buffer.
// (== R9, the verified best at ~108 us. R10's TLP attempt regressed:
// occupancy 2x -> MfmaUtil flat 54%, LDS-read/FLOP doubled. The ~55%
// MfmaUtil is structural for this tile/sync design; R11 leaves the GEMM
// untouched and attacks the constant ~85 us of non-GEMM pipeline time.)
__global__ void __launch_bounds__(256, 2)
gemm_min_kernel(const uint8_t* __restrict__ Ah8, const uint8_t* __restrict__ Bh8,
                const float* __restrict__ sq2, float* __restrict__ ws_min) {
  __shared__ __align__(16) uint8_t lsB[2][4 * BNT * BKP];   // 2 x 32 KB
  __shared__ __align__(16) float sq2_lds[CHUNK_ROWS];       // 8 KB

  const int tid = threadIdx.x;
  const int lane = tid & 63;
  const int wv = tid >> 6;       // 0..3
  const int fr = lane & 15;
  const int kg = lane >> 4;      // 0..3
  const int frs = fr & 7;

  const int bid = blockIdx.x;
  const int chunk = bid & 7;
  const int rowBase = (bid >> 3) * BM;
  const int colBase0 = chunk * CHUNK_ROWS;

  const int cis = lane >> 3;                       // col in slot
  const int kofs_st = (((lane & 7) ^ cis) << 4);   // swizzled 16B source chunk

  // ---- Persistent A fragments: areg[i][p] = row (rowBase+wv*64+i*16+fr),
  // k = p*128 + kg*32 .. +32 (32 bytes = 8 VGPRs each; 16 frags = 128 VGPRs).
  intx8 areg[4][4];
  {
    const uint8_t* abase = Ah8 + (size_t)(rowBase + wv * 64 + fr) * KDIM + kg * 32;
    #pragma unroll
    for (int i = 0; i < 4; i++)
      #pragma unroll
      for (int p = 0; p < 4; p++) {
        const uint8_t* ap = abase + (size_t)i * 16 * KDIM + p * BKP;
        intx4 lo = *(const intx4*)ap;
        intx4 hi = *(const intx4*)(ap + 16);
        areg[i][p] = __builtin_shufflevector(lo, hi, 0, 1, 2, 3, 4, 5, 6, 7);
      }
  }

  // Running MAX of (inner - sq2/2); ws_min = -2 * runmax at the end.
  float runmax[4][4];
  #pragma unroll
  for (int i = 0; i < 4; i++)
    #pragma unroll
    for (int r4 = 0; r4 < 4; r4++) runmax[i][r4] = -3.0e38f;

  // Stage one full 64-col x K=512 tile (32 KB): 8 calls per wave.
  #define STAGE_TILE(buf, cb)                                                 \
    {                                                                         \
      _Pragma("unroll")                                                       \
      for (int p_ = 0; p_ < 4; ++p_) {                                        \
        _Pragma("unroll")                                                     \
        for (int c_ = 0; c_ < 2; ++c_) {                                      \
          const int slot = wv * 2 + c_;                                       \
          async_ld16(Bh8 + (size_t)((cb) + slot * 8 + cis) * KDIM +           \
                         p_ * BKP + kofs_st,                                  \
                     (buf) + p_ * (BNT * BKP) + (slot << 10));                \
        }                                                                     \
      }                                                                       \
    }

  // Prologue: sq2 chunk -> LDS (8 KB, linear both sides; 2 calls/wave),
  // then stage tile 0.
  {
    const uint8_t* s2src = (const uint8_t*)(sq2 + colBase0);
    #pragma unroll
    for (int c = 0; c < 2; ++c) {
      const int off = ((wv * 2 + c) << 10);
      async_ld16(s2src + off + lane * 16, ((uint8_t*)sq2_lds) + off);
    }
  }
  STAGE_TILE(lsB[0], colBase0)

  for (int bt = 0; bt < BT_PER_CHUNK; ++bt) {
    asm volatile("s_waitcnt vmcnt(0)" ::: "memory");
    __builtin_amdgcn_s_barrier();
    __builtin_amdgcn_sched_barrier(0);

    if (bt + 1 < BT_PER_CHUNK) {
      STAGE_TILE(lsB[(bt + 1) & 1], colBase0 + (bt + 1) * BNT)
    }

    const uint8_t* cur = lsB[bt & 1];

    // sq2-folded accumulator init: acc[i][j] = -sq2[col]/2 (per-j value).
    float s2h[4];
    #pragma unroll
    for (int j = 0; j < 4; j++)
      s2h[j] = -0.5f * sq2_lds[bt * BNT + j * 16 + fr];
    floatx4 acc[4][4];
    #pragma unroll
    for (int i = 0; i < 4; i++)
      #pragma unroll
      for (int j = 0; j < 4; j++)
        acc[i][j] = (floatx4){s2h[j], s2h[j], s2h[j], s2h[j]};

    // Straight-line tile body: 32 ds_read_b128 + 64 MFMAs, no barriers.
    __builtin_amdgcn_s_setprio(1);
    #pragma unroll
    for (int p = 0; p < 4; ++p) {
      #pragma unroll
      for (int j = 0; j < 4; ++j) {
        const uint8_t* bp = cur + p * (BNT * BKP) + (j * 16 + fr) * BKP;
        intx4 lo = *(const intx4*)(bp + ((((kg << 1)) ^ frs) << 4));
        intx4 hi = *(const intx4*)(bp + ((((kg << 1) | 1) ^ frs) << 4));
        intx8 bv = __builtin_shufflevector(lo, hi, 0, 1, 2, 3, 4, 5, 6, 7);
        #pragma unroll
        for (int i = 0; i < 4; i++)
          acc[i][j] = __builtin_amdgcn_mfma_scale_f32_16x16x128_f8f6f4(
              areg[i][p], bv, acc[i][j], 0, 0,
              0, UNIT_SCALE, 0, UNIT_SCALE);
      }
    }
    __builtin_amdgcn_s_setprio(0);

    // Epilogue: pure running max (fmaf eliminated by the init fold).
    #pragma unroll
    for (int j = 0; j < 4; j++)
      #pragma unroll
      for (int i = 0; i < 4; i++)
        #pragma unroll
        for (int r4 = 0; r4 < 4; r4++)
          runmax[i][r4] = fmaxf(runmax[i][r4], acc[i][j][r4]);
  }

  // Max over the 16 columns per lane row-group: butterfly on lane bits 0..3.
  #pragma unroll
  for (int i = 0; i < 4; i++)
    #pragma unroll
    for (int r4 = 0; r4 < 4; r4++) {
      float v = runmax[i][r4];
      v = fmaxf(v, __shfl_xor(v, 1, 64));
      v = fmaxf(v, __shfl_xor(v, 2, 64));
      v = fmaxf(v, __shfl_xor(v, 4, 64));
      v = fmaxf(v, __shfl_xor(v, 8, 64));
      runmax[i][r4] = v;
    }

  if (fr == 0) {
    #pragma unroll
    for (int i = 0; i < 4; i++)
      #pragma unroll
      for (int r4 = 0; r4 < 4; r4++) {
        const int lrow = wv * 64 + i * 16 + kg * 4 + r4;
        ws_min[(size_t)chunk * N_ROWS + rowBase + lrow] = -2.f * runmax[i][r4];
      }
  }
}

// Kernel 3 (R11: partial+final merged): single-block finisher.
// 1024 threads; each handles 16 rows (strided, coalesced): min across
// chunks + sqrt/relu, then deterministic block tree-reduction -> mean.
// ~576 KB read by one block (~5 us) but saves one launch + gap.
__global__ void finish_kernel(const float* __restrict__ ws_min,
                              const float* __restrict__ sq1,
                              float* __restrict__ out) {
  const int tid = threadIdx.x;
  float s = 0.f;
  for (int r = tid; r < N_ROWS; r += 1024) {
    float m = ws_min[r];
    #pragma unroll
    for (int c = 1; c < NCHUNK; c++)
      m = fminf(m, ws_min[(size_t)c * N_ROWS + r]);
    float d2 = sq1[r] + m;
    d2 = d2 > 0.f ? d2 : 0.f;
    float v = sqrtf(d2) - 0.1f;
    s += (v > 0.f ? v : 0.f);
  }
  #pragma unroll
  for (int off = 32; off; off >>= 1) s += __shfl_down(s, off, 64);
  __shared__ float ps[16];
  if ((tid & 63) == 0) ps[tid >> 6] = s;
  __syncthreads();
  if (tid < 64) {
    float t = (tid < 16) ? ps[tid] : 0.f;
    #pragma unroll
    for (int off = 8; off; off >>= 1) t += __shfl_down(t, off, 64);
    if (tid == 0) out[0] = t / (float)N_ROWS;
  }
}

extern "C" void kernel_launch(void* const* d_in, const int* in_sizes, int n_in,
                              void* d_out, int out_size, void* d_ws, size_t ws_size,
                              hipStream_t stream) {
  const float* A = (const float*)d_in[0];
  const float* B = (const float*)d_in[1];
  char* ws = (char*)d_ws;
  const size_t fp8Bytes = (size_t)N_ROWS * KDIM;   // 8 MiB each
  uint8_t* Ah8 = (uint8_t*)ws;
  uint8_t* Bh8 = (uint8_t*)(ws + fp8Bytes);
  float* sq1 = (float*)(ws + 2 * fp8Bytes);
  float* sq2 = sq1 + N_ROWS;
  float* ws_min = sq2 + M_ROWS;

  conv_kernel<<<dim3((N_ROWS + M_ROWS) / 4), dim3(256), 0, stream>>>(A, B, Ah8, Bh8, sq1, sq2);
  gemm_min_kernel<<<dim3((N_ROWS / BM) * NCHUNK), dim3(256), 0, stream>>>(Ah8, Bh8, sq2, ws_min);
  finish_kernel<<<dim3(1), dim3(1024), 0, stream>>>(ws_min, sq1, (float*)d_out);
}

// Round 13
// 192.107 us; speedup vs baseline: 1.0619x; 1.0142x over previous
//
#include <hip/hip_runtime.h>
#include <stdint.h>

#define N_ROWS 16384
#define M_ROWS 16384
#define KDIM   512
#define BM 256           // 4 waves x 64 rows
#define BNT 64           // cols per bt tile
#define BKP 128          // k per phase-sub-buffer (one MFMA K)
#define NCHUNK 8
#define CHUNK_ROWS (M_ROWS / NCHUNK)       // 2048
#define BT_PER_CHUNK (CHUNK_ROWS / BNT)    // 32

typedef int intx4 __attribute__((ext_vector_type(4)));
typedef int intx8 __attribute__((ext_vector_type(8)));
typedef float floatx4 __attribute__((ext_vector_type(4)));

#define UNIT_SCALE 0x7F7F7F7F  // E8M0 exponent 127 -> 2^0 = 1.0 in every byte

__device__ __forceinline__ void async_ld16(const uint8_t* g, uint8_t* l) {
  __builtin_amdgcn_global_load_lds(
      (const __attribute__((address_space(1))) void*)g,
      (__attribute__((address_space(3))) void*)l, 16, 0, 0);
}

// Kernel 1: fp32 -> fp8 e4m3 (unit scale) + per-row squared norms.
// One wave per row; lane-contiguous float4 loads, coalesced dword stores.
__global__ void conv_kernel(const float* __restrict__ A, const float* __restrict__ B,
                            uint8_t* __restrict__ Ah8, uint8_t* __restrict__ Bh8,
                            float* __restrict__ sq1, float* __restrict__ sq2) {
  const int lane = threadIdx.x & 63;
  const int wv = threadIdx.x >> 6;
  int row = blockIdx.x * 4 + wv;
  const float* src;
  uint8_t* dst;
  float* sq;
  if (row < N_ROWS) {
    src = A + (size_t)row * KDIM;
    dst = Ah8 + (size_t)row * KDIM;
    sq = sq1 + row;
  } else {
    int r = row - N_ROWS;
    src = B + (size_t)r * KDIM;
    dst = Bh8 + (size_t)r * KDIM;
    sq = sq2 + r;
  }
  const float4* s4 = (const float4*)src;
  float4 v0 = s4[lane];
  float4 v1 = s4[lane + 64];
  uint32_t w0 = 0, w1 = 0;
  w0 = __builtin_amdgcn_cvt_pk_fp8_f32(v0.x, v0.y, w0, 0);
  w0 = __builtin_amdgcn_cvt_pk_fp8_f32(v0.z, v0.w, w0, 1);
  w1 = __builtin_amdgcn_cvt_pk_fp8_f32(v1.x, v1.y, w1, 0);
  w1 = __builtin_amdgcn_cvt_pk_fp8_f32(v1.z, v1.w, w1, 1);
  ((uint32_t*)dst)[lane] = w0;
  ((uint32_t*)dst)[64 + lane] = w1;
  float s = v0.x * v0.x + v0.y * v0.y + v0.z * v0.z + v0.w * v0.w
          + v1.x * v1.x + v1.y * v1.y + v1.z * v1.z + v1.w * v1.w;
  #pragma unroll
  for (int off = 32; off; off >>= 1) s += __shfl_down(s, off, 64);
  if (lane == 0) *sq = s;
}

// Kernel 2: fused fp8 GEMM + running-min, TILE-granular double buffer,
// R12: split-j accumulator to halve register residency.
//
// R11 discovery: VGPR_Count=120 but areg alone = 128 regs -> areg(128) +
// acc(64) live in the unified AGPR/VGPR file => ~312 regs/wave > 256 =>
// only ONE wave resident per SIMD. That voids every cross-wave overlap
// attempt (R5 stagger, R6 interleave, R8 setprio — all no-ops with no
// SIMD-mate) and explains the immovable 56% MfmaUtil (= pure intra-wave
// compiler pipelining). R12: process the tile's 4 column groups in TWO
// sequential halves with acc[4][2] (32 regs, declared inside the half) --
// footprint ~220 <= 256 -> true 2 waves/SIMD. Same MFMA count, same LDS
// read count (reordered), same VALU. #pragma unroll 1 on the half loop so
// the compiler cannot re-merge the two halves' live ranges.
__global__ void __launch_bounds__(256, 2)
gemm_min_kernel(const uint8_t* __restrict__ Ah8, const uint8_t* __restrict__ Bh8,
                const float* __restrict__ sq2, float* __restrict__ ws_min) {
  __shared__ __align__(16) uint8_t lsB[2][4 * BNT * BKP];   // 2 x 32 KB
  __shared__ __align__(16) float sq2_lds[CHUNK_ROWS];       // 8 KB

  const int tid = threadIdx.x;
  const int lane = tid & 63;
  const int wv = tid >> 6;       // 0..3
  const int fr = lane & 15;
  const int kg = lane >> 4;      // 0..3
  const int frs = fr & 7;

  const int bid = blockIdx.x;
  const int chunk = bid & 7;
  const int rowBase = (bid >> 3) * BM;
  const int colBase0 = chunk * CHUNK_ROWS;

  const int cis = lane >> 3;                       // col in slot
  const int kofs_st = (((lane & 7) ^ cis) << 4);   // swizzled 16B source chunk

  // ---- Persistent A fragments: areg[i][p] = row (rowBase+wv*64+i*16+fr),
  // k = p*128 + kg*32 .. +32 (32 bytes = 8 VGPRs each; 16 frags = 128 regs).
  intx8 areg[4][4];
  {
    const uint8_t* abase = Ah8 + (size_t)(rowBase + wv * 64 + fr) * KDIM + kg * 32;
    #pragma unroll
    for (int i = 0; i < 4; i++)
      #pragma unroll
      for (int p = 0; p < 4; p++) {
        const uint8_t* ap = abase + (size_t)i * 16 * KDIM + p * BKP;
        intx4 lo = *(const intx4*)ap;
        intx4 hi = *(const intx4*)(ap + 16);
        areg[i][p] = __builtin_shufflevector(lo, hi, 0, 1, 2, 3, 4, 5, 6, 7);
      }
  }

  // Running MAX of (inner - sq2/2); ws_min = -2 * runmax at the end.
  float runmax[4][4];
  #pragma unroll
  for (int i = 0; i < 4; i++)
    #pragma unroll
    for (int r4 = 0; r4 < 4; r4++) runmax[i][r4] = -3.0e38f;

  // Stage one full 64-col x K=512 tile (32 KB): 8 calls per wave.
  #define STAGE_TILE(buf, cb)                                                 \
    {                                                                         \
      _Pragma("unroll")                                                       \
      for (int p_ = 0; p_ < 4; ++p_) {                                        \
        _Pragma("unroll")                                                     \
        for (int c_ = 0; c_ < 2; ++c_) {                                      \
          const int slot = wv * 2 + c_;                                       \
          async_ld16(Bh8 + (size_t)((cb) + slot * 8 + cis) * KDIM +           \
                         p_ * BKP + kofs_st,                                  \
                     (buf) + p_ * (BNT * BKP) + (slot << 10));                \
        }                                                                     \
      }                                                                       \
    }

  // Prologue: sq2 chunk -> LDS, then stage tile 0.
  {
    const uint8_t* s2src = (const uint8_t*)(sq2 + colBase0);
    #pragma unroll
    for (int c = 0; c < 2; ++c) {
      const int off = ((wv * 2 + c) << 10);
      async_ld16(s2src + off + lane * 16, ((uint8_t*)sq2_lds) + off);
    }
  }
  STAGE_TILE(lsB[0], colBase0)

  for (int bt = 0; bt < BT_PER_CHUNK; ++bt) {
    asm volatile("s_waitcnt vmcnt(0)" ::: "memory");
    __builtin_amdgcn_s_barrier();
    __builtin_amdgcn_sched_barrier(0);

    if (bt + 1 < BT_PER_CHUNK) {
      STAGE_TILE(lsB[(bt + 1) & 1], colBase0 + (bt + 1) * BNT)
    }

    const uint8_t* cur = lsB[bt & 1];

    // R12: two sequential column-half passes, each with a 32-reg acc.
    #pragma unroll 1
    for (int jh = 0; jh < 2; ++jh) {
      float s2h[2];
      #pragma unroll
      for (int jj = 0; jj < 2; jj++)
        s2h[jj] = -0.5f * sq2_lds[bt * BNT + (jh * 2 + jj) * 16 + fr];

      floatx4 acc[4][2];
      #pragma unroll
      for (int i = 0; i < 4; i++)
        #pragma unroll
        for (int jj = 0; jj < 2; jj++)
          acc[i][jj] = (floatx4){s2h[jj], s2h[jj], s2h[jj], s2h[jj]};

      __builtin_amdgcn_s_setprio(1);
      #pragma unroll
      for (int p = 0; p < 4; ++p) {
        #pragma unroll
        for (int jj = 0; jj < 2; ++jj) {
          const uint8_t* bp =
              cur + p * (BNT * BKP) + ((jh * 2 + jj) * 16 + fr) * BKP;
          intx4 lo = *(const intx4*)(bp + ((((kg << 1)) ^ frs) << 4));
          intx4 hi = *(const intx4*)(bp + ((((kg << 1) | 1) ^ frs) << 4));
          intx8 bv = __builtin_shufflevector(lo, hi, 0, 1, 2, 3, 4, 5, 6, 7);
          #pragma unroll
          for (int i = 0; i < 4; i++)
            acc[i][jj] = __builtin_amdgcn_mfma_scale_f32_16x16x128_f8f6f4(
                areg[i][p], bv, acc[i][jj], 0, 0,
                0, UNIT_SCALE, 0, UNIT_SCALE);
        }
      }
      __builtin_amdgcn_s_setprio(0);

      // Epilogue for this half: pure running max.
      #pragma unroll
      for (int jj = 0; jj < 2; jj++)
        #pragma unroll
        for (int i = 0; i < 4; i++)
          #pragma unroll
          for (int r4 = 0; r4 < 4; r4++)
            runmax[i][r4] = fmaxf(runmax[i][r4], acc[i][jj][r4]);
    }
  }

  // Max over the 16 columns per lane row-group: butterfly on lane bits 0..3.
  #pragma unroll
  for (int i = 0; i < 4; i++)
    #pragma unroll
    for (int r4 = 0; r4 < 4; r4++) {
      float v = runmax[i][r4];
      v = fmaxf(v, __shfl_xor(v, 1, 64));
      v = fmaxf(v, __shfl_xor(v, 2, 64));
      v = fmaxf(v, __shfl_xor(v, 4, 64));
      v = fmaxf(v, __shfl_xor(v, 8, 64));
      runmax[i][r4] = v;
    }

  if (fr == 0) {
    #pragma unroll
    for (int i = 0; i < 4; i++)
      #pragma unroll
      for (int r4 = 0; r4 < 4; r4++) {
        const int lrow = wv * 64 + i * 16 + kg * 4 + r4;
        ws_min[(size_t)chunk * N_ROWS + rowBase + lrow] = -2.f * runmax[i][r4];
      }
  }
}

// Kernel 3: single-block finisher (min across chunks + sqrt/relu + mean).
__global__ void finish_kernel(const float* __restrict__ ws_min,
                              const float* __restrict__ sq1,
                              float* __restrict__ out) {
  const int tid = threadIdx.x;
  float s = 0.f;
  for (int r = tid; r < N_ROWS; r += 1024) {
    float m = ws_min[r];
    #pragma unroll
    for (int c = 1; c < NCHUNK; c++)
      m = fminf(m, ws_min[(size_t)c * N_ROWS + r]);
    float d2 = sq1[r] + m;
    d2 = d2 > 0.f ? d2 : 0.f;
    float v = sqrtf(d2) - 0.1f;
    s += (v > 0.f ? v : 0.f);
  }
  #pragma unroll
  for (int off = 32; off; off >>= 1) s += __shfl_down(s, off, 64);
  __shared__ float ps[16];
  if ((tid & 63) == 0) ps[tid >> 6] = s;
  __syncthreads();
  if (tid < 64) {
    float t = (tid < 16) ? ps[tid] : 0.f;
    #pragma unroll
    for (int off = 8; off; off >>= 1) t += __shfl_down(t, off, 64);
    if (tid == 0) out[0] = t / (float)N_ROWS;
  }
}

extern "C" void kernel_launch(void* const* d_in, const int* in_sizes, int n_in,
                              void* d_out, int out_size, void* d_ws, size_t ws_size,
                              hipStream_t stream) {
  const float* A = (const float*)d_in[0];
  const float* B = (const float*)d_in[1];
  char* ws = (char*)d_ws;
  const size_t fp8Bytes = (size_t)N_ROWS * KDIM;   // 8 MiB each
  uint8_t* Ah8 = (uint8_t*)ws;
  uint8_t* Bh8 = (uint8_t*)(ws + fp8Bytes);
  float* sq1 = (float*)(ws + 2 * fp8Bytes);
  float* sq2 = sq1 + N_ROWS;
  float* ws_min = sq2 + M_ROWS;

  conv_kernel<<<dim3((N_ROWS + M_ROWS) / 4), dim3(256), 0, stream>>>(A, B, Ah8, Bh8, sq1, sq2);
  gemm_min_kernel<<<dim3((N_ROWS / BM) * NCHUNK), dim3(256), 0, stream>>>(Ah8, Bh8, sq2, ws_min);
  finish_kernel<<<dim3(1), dim3(1024), 0, stream>>>(ws_min, sq1, (float*)d_out);
}